// Round 1
// 659.198 us; speedup vs baseline: 1.0012x; 1.0012x over previous
//
#include <hip/hip_runtime.h>
#include <hip/hip_bf16.h>

#define NROW 1024
#define DDIM 512
#define CDIM 85742
#define SSC 64.0f
#define MARG 0.5f
#define AEPS 1e-7f

typedef __attribute__((ext_vector_type(8))) short bf16x8;
typedef __attribute__((ext_vector_type(4))) float f32x4;

__device__ __forceinline__ void async_ld16(const void* g, void* l) {
  __builtin_amdgcn_global_load_lds((const __attribute__((address_space(1))) void*)g,
                                   (__attribute__((address_space(3))) void*)l, 16, 0, 0);
}

__device__ __forceinline__ bf16x8 cvt8(f32x4 lo, f32x4 hi) {
  __hip_bfloat16 t[8];
  t[0] = __float2bfloat16(lo.x); t[1] = __float2bfloat16(lo.y);
  t[2] = __float2bfloat16(lo.z); t[3] = __float2bfloat16(lo.w);
  t[4] = __float2bfloat16(hi.x); t[5] = __float2bfloat16(hi.y);
  t[6] = __float2bfloat16(hi.z); t[7] = __float2bfloat16(hi.w);
  return *(bf16x8*)t;
}

// One wave per row: L2-normalize x row, emit bf16. Also zeroes rowsum[row].
__global__ void row_normalize(const float* __restrict__ x, __hip_bfloat16* __restrict__ xn,
                              float* __restrict__ rowsum) {
  const int row = blockIdx.x;
  const int lane = threadIdx.x;  // 64 threads
  if (lane == 0) rowsum[row] = 0.0f;
  const float4* xr = (const float4*)(x + (size_t)row * DDIM);
  float4 a = xr[lane * 2 + 0];
  float4 b = xr[lane * 2 + 1];
  float ss = a.x * a.x + a.y * a.y + a.z * a.z + a.w * a.w +
             b.x * b.x + b.y * b.y + b.z * b.z + b.w * b.w;
#pragma unroll
  for (int o = 32; o >= 1; o >>= 1) ss += __shfl_xor(ss, o);
  const float inv = 1.0f / fmaxf(sqrtf(ss), 1e-12f);
  __hip_bfloat16 t[8];
  t[0] = __float2bfloat16(a.x * inv); t[1] = __float2bfloat16(a.y * inv);
  t[2] = __float2bfloat16(a.z * inv); t[3] = __float2bfloat16(a.w * inv);
  t[4] = __float2bfloat16(b.x * inv); t[5] = __float2bfloat16(b.y * inv);
  t[6] = __float2bfloat16(b.z * inv); t[7] = __float2bfloat16(b.w * inv);
  *(bf16x8*)(xn + (size_t)row * DDIM + lane * 8) = *(bf16x8*)t;
}

// Grid-stride: convert W fp32 -> bf16 once (kills the 8x-redundant per-tile
// conversion in the GEMM). Nontemporal read: fp32 W is dead after this.
__global__ void w_to_bf16(const float* __restrict__ W, __hip_bfloat16* __restrict__ Wb) {
  const size_t total = (size_t)CDIM * DDIM / 8;
  const size_t stride = (size_t)gridDim.x * blockDim.x;
  for (size_t i = (size_t)blockIdx.x * blockDim.x + threadIdx.x; i < total; i += stride) {
    const f32x4* p = (const f32x4*)(W + i * 8);
    f32x4 a = __builtin_nontemporal_load(p);
    f32x4 b = __builtin_nontemporal_load(p + 1);
    *(bf16x8*)(Wb + i * 8) = cvt8(a, b);
  }
}

// 128x128 tile, BK=32, 4 waves (2x2), 16x16x32 bf16 MFMA.
// WB16=1: both A and B staged as bf16 via global_load_lds width=16, XOR-swizzled
//   source chunks (linear LDS dest; swizzle applied at source + at read — rule 21).
// WB16=0: fallback (small workspace): B staged fp32 + converted at frag read.
// Grid: 1-D 5376. id&7 selects an XCD-stripe of 84 column-tiles; the 8 M-tiles
// of one column dispatch within 64 ids on the same XCD -> W slab L2-hit.
template <int WB16>
__global__ __launch_bounds__(256) void gemm_loss(const __hip_bfloat16* __restrict__ A,
                                                 const __hip_bfloat16* __restrict__ Wb,
                                                 const float* __restrict__ W,
                                                 float* __restrict__ wf,
                                                 float* __restrict__ rowsum) {
  const int id = blockIdx.x;
  const int xcd = id & 7;
  const int s = id >> 3;
  const int ctile = xcd * 84 + (s >> 3);
  if (ctile >= 670) return;  // 16 pad blocks
  const int mtile = s & 7;

  __shared__ __align__(16) char smem[WB16 ? (8192 + 8192) : (8192 + 16384)];
  __hip_bfloat16* As = (__hip_bfloat16*)smem;                    // 128x32 bf16, 8 KB
  __hip_bfloat16* Bs16 = (__hip_bfloat16*)(smem + 8192);         // 128x32 bf16, 8 KB
  float* Bs32 = (float*)(smem + 8192);                           // 128x32 fp32, 16 KB

  const int tid = threadIdx.x;
  const int lane = tid & 63;
  const int wav = tid >> 6;
  const int wm = wav >> 1, wn = wav & 1;
  const int row0 = mtile * 128;
  const int col0 = ctile * 128;
  const int lr = lane & 15, lq = lane >> 4;
  const int waveBase = tid & ~63;

  f32x4 acc[4][4] = {};

  for (int k0 = 0; k0 < DDIM; k0 += 32) {
    // ---- stage A tile (128x32 bf16 = 8KB): 512 chunks of 16B, XOR-swizzled src
#pragma unroll
    for (int q = 0; q < 2; ++q) {
      const int chunk = q * 256 + tid;
      const int r = chunk >> 2, kc = chunk & 3;
      const int kcs = kc ^ (r & 3);  // slot kc holds global chunk kc^(r&3)
      async_ld16(A + ((size_t)(row0 + r) * DDIM + k0 + kcs * 8),
                 As + (q * 256 + waveBase) * 8);
    }
    if constexpr (WB16) {
      // ---- stage B tile (128x32 bf16 = 8KB): same pattern as A
#pragma unroll
      for (int q = 0; q < 2; ++q) {
        const int chunk = q * 256 + tid;
        const int r = chunk >> 2, kc = chunk & 3;
        const int kcs = kc ^ (r & 3);
        int gr = col0 + r;
        gr = gr < CDIM ? gr : CDIM - 1;  // clamp address; masked in epilogue
        async_ld16(Wb + ((size_t)gr * DDIM + k0 + kcs * 8),
                   Bs16 + (q * 256 + waveBase) * 8);
      }
    } else {
      // ---- stage B tile fp32 (128x32 = 16KB): 1024 chunks of 16B, XOR swizzle
#pragma unroll
      for (int q = 0; q < 4; ++q) {
        const int chunk = q * 256 + tid;
        const int r = chunk >> 3, kc = chunk & 7;
        const int kcs = kc ^ (r & 7);
        int gr = col0 + r;
        gr = gr < CDIM ? gr : CDIM - 1;
        async_ld16(W + ((size_t)gr * DDIM + k0 + kcs * 4),
                   Bs32 + (q * 256 + waveBase) * 4);
      }
    }
    __syncthreads();

    // ---- fragments + MFMA
    bf16x8 af[4], bfr[4];
#pragma unroll
    for (int i = 0; i < 4; ++i) {
      const int ar = wm * 64 + i * 16 + lr;
      af[i] = *(const bf16x8*)(As + ar * 32 + (lq ^ (ar & 3)) * 8);
    }
    if constexpr (WB16) {
#pragma unroll
      for (int j = 0; j < 4; ++j) {
        const int br = wn * 64 + j * 16 + lr;
        bfr[j] = *(const bf16x8*)(Bs16 + br * 32 + (lq ^ (br & 3)) * 8);
      }
    } else {
#pragma unroll
      for (int j = 0; j < 4; ++j) {
        const int br = wn * 64 + j * 16 + lr;
        const int s0 = (2 * lq) ^ (br & 7);
        const int s1 = (2 * lq + 1) ^ (br & 7);
        f32x4 lo = *(const f32x4*)(Bs32 + br * 32 + s0 * 4);
        f32x4 hi = *(const f32x4*)(Bs32 + br * 32 + s1 * 4);
        bfr[j] = cvt8(lo, hi);
      }
    }
#pragma unroll
    for (int i = 0; i < 4; ++i)
#pragma unroll
      for (int j = 0; j < 4; ++j)
        acc[i][j] = __builtin_amdgcn_mfma_f32_16x16x32_bf16(af[i], bfr[j], acc[i][j], 0, 0, 0);
    __syncthreads();
  }

  // ---- epilogue: store wf (nontemporal: 351 MB stream, keep W in L3),
  // per-row exp-sum partials
#pragma unroll
  for (int i = 0; i < 4; ++i) {
    const int rb = row0 + wm * 64 + i * 16 + lq * 4;
#pragma unroll
    for (int r = 0; r < 4; ++r) {
      const int grow = rb + r;
      float esum = 0.f;
#pragma unroll
      for (int j = 0; j < 4; ++j) {
        const int gcol = col0 + wn * 64 + j * 16 + lr;
        const float v = acc[i][j][r];
        if (gcol < CDIM) {
          __builtin_nontemporal_store(v, wf + (size_t)grow * CDIM + gcol);
          esum += __expf(SSC * v);
        }
      }
      esum += __shfl_xor(esum, 1);
      esum += __shfl_xor(esum, 2);
      esum += __shfl_xor(esum, 4);
      esum += __shfl_xor(esum, 8);
      if (lr == 0) atomicAdd(rowsum + grow, esum);
    }
  }
}

// One block, 1024 threads: arcface loss from wf + rowsum.
__global__ void finalize(const float* __restrict__ wf, const float* __restrict__ rowsum,
                         const int* __restrict__ labels, float* __restrict__ out_loss) {
  const int i = threadIdx.x;
  const int lab = labels[i];
  const float tgt = wf[(size_t)i * CDIM + lab];
  const float tc = fminf(fmaxf(tgt, -1.0f + AEPS), 1.0f - AEPS);
  const float num = SSC * cosf(acosf(tc) + MARG);
  const float excl = rowsum[i] - __expf(SSC * tgt);
  float L = num - logf(__expf(num) + excl);
#pragma unroll
  for (int o = 32; o >= 1; o >>= 1) L += __shfl_xor(L, o);
  __shared__ float red[16];
  if ((i & 63) == 0) red[i >> 6] = L;
  __syncthreads();
  if (i < 64) {
    float v = (i < 16) ? red[i] : 0.f;
#pragma unroll
    for (int o = 8; o >= 1; o >>= 1) v += __shfl_xor(v, o);
    if (i == 0) out_loss[0] = -v * (1.0f / NROW);
  }
}

extern "C" void kernel_launch(void* const* d_in, const int* in_sizes, int n_in,
                              void* d_out, int out_size, void* d_ws, size_t ws_size,
                              hipStream_t stream) {
  const float* x = (const float*)d_in[0];
  const float* W = (const float*)d_in[1];
  const int* labels = (const int*)d_in[2];
  float* out = (float*)d_out;

  // workspace layout:
  //   [0,4K)            rowsum fp32[1024]
  //   [4K, 4K+1M)       xn bf16[1024*512]
  //   [4K+1M, +87.8M)   Wb bf16[85742*512]   (only if ws_size permits)
  float* rowsum = (float*)d_ws;
  __hip_bfloat16* xn = (__hip_bfloat16*)((char*)d_ws + 4096);
  const size_t wb_off = 4096 + (size_t)NROW * DDIM * 2;
  const size_t need = wb_off + (size_t)CDIM * DDIM * 2;  // ~84.7 MiB
  __hip_bfloat16* Wb = (__hip_bfloat16*)((char*)d_ws + wb_off);

  row_normalize<<<NROW, 64, 0, stream>>>(x, xn, rowsum);
  if (ws_size >= need) {
    w_to_bf16<<<2048, 256, 0, stream>>>(W, Wb);
    gemm_loss<1><<<672 * 8, 256, 0, stream>>>(xn, Wb, nullptr, out, rowsum);
  } else {
    gemm_loss<0><<<672 * 8, 256, 0, stream>>>(xn, nullptr, W, out, rowsum);
  }
  finalize<<<1, 1024, 0, stream>>>(out, rowsum, labels, out + (size_t)NROW * CDIM);
}

// Round 2
// 645.385 us; speedup vs baseline: 1.0226x; 1.0214x over previous
//
#include <hip/hip_runtime.h>
#include <hip/hip_bf16.h>

#define NROW 1024
#define DDIM 512
#define CDIM 85742
#define SSC 64.0f
#define MARG 0.5f
#define AEPS 1e-7f

typedef __attribute__((ext_vector_type(8))) short bf16x8;
typedef __attribute__((ext_vector_type(4))) float f32x4;

__device__ __forceinline__ void async_ld16(const void* g, void* l) {
  __builtin_amdgcn_global_load_lds((const __attribute__((address_space(1))) void*)g,
                                   (__attribute__((address_space(3))) void*)l, 16, 0, 0);
}

__device__ __forceinline__ bf16x8 cvt8(f32x4 lo, f32x4 hi) {
  __hip_bfloat16 t[8];
  t[0] = __float2bfloat16(lo.x); t[1] = __float2bfloat16(lo.y);
  t[2] = __float2bfloat16(lo.z); t[3] = __float2bfloat16(lo.w);
  t[4] = __float2bfloat16(hi.x); t[5] = __float2bfloat16(hi.y);
  t[6] = __float2bfloat16(hi.z); t[7] = __float2bfloat16(hi.w);
  return *(bf16x8*)t;
}

// Fused prep: blocks [0,2048) convert W fp32->bf16 (grid-stride, NT reads:
// fp32 W is dead afterwards); blocks [2048,2304) L2-normalize x rows (one
// wave per row) and zero rowsum. Saves a launch vs separate kernels.
__global__ __launch_bounds__(256) void prep(const float* __restrict__ x,
                                            const float* __restrict__ W,
                                            __hip_bfloat16* __restrict__ xn,
                                            __hip_bfloat16* __restrict__ Wb,
                                            float* __restrict__ rowsum) {
  const int bid = blockIdx.x;
  if (bid >= 2048) {
    const int row = ((bid - 2048) << 2) + (threadIdx.x >> 6);
    const int lane = threadIdx.x & 63;
    if (lane == 0) rowsum[row] = 0.0f;
    const float4* xr = (const float4*)(x + (size_t)row * DDIM);
    float4 a = xr[lane * 2 + 0];
    float4 b = xr[lane * 2 + 1];
    float ss = a.x * a.x + a.y * a.y + a.z * a.z + a.w * a.w +
               b.x * b.x + b.y * b.y + b.z * b.z + b.w * b.w;
#pragma unroll
    for (int o = 32; o >= 1; o >>= 1) ss += __shfl_xor(ss, o);
    const float inv = 1.0f / fmaxf(sqrtf(ss), 1e-12f);
    __hip_bfloat16 t[8];
    t[0] = __float2bfloat16(a.x * inv); t[1] = __float2bfloat16(a.y * inv);
    t[2] = __float2bfloat16(a.z * inv); t[3] = __float2bfloat16(a.w * inv);
    t[4] = __float2bfloat16(b.x * inv); t[5] = __float2bfloat16(b.y * inv);
    t[6] = __float2bfloat16(b.z * inv); t[7] = __float2bfloat16(b.w * inv);
    *(bf16x8*)(xn + (size_t)row * DDIM + lane * 8) = *(bf16x8*)t;
    return;
  }
  const size_t total = (size_t)CDIM * DDIM / 8;  // 5,487,488 (exact)
  const size_t stride = (size_t)2048 * 256;
  for (size_t i = (size_t)bid * 256 + threadIdx.x; i < total; i += stride) {
    const f32x4* p = (const f32x4*)(W + i * 8);
    f32x4 a = __builtin_nontemporal_load(p);
    f32x4 b = __builtin_nontemporal_load(p + 1);
    *(bf16x8*)(Wb + i * 8) = cvt8(a, b);
  }
}

// 256x128 tile (BM=256 doubles Wb reuse: per-XCD B slab is 10.8MB > 4MB L2,
// so B comes from L3 -- halving the L3->CU B traffic was the round-1 limiter).
// BK=32, 8 waves (4M x 2N), 512 threads, 16x16x32 bf16 MFMA, per-wave 64x64
// output (acc[4][4], same verified frag structure as round 1).
// Double-buffered LDS (T3-minimum 2-phase): stage tile k+1 while computing k;
// one barrier per K-step (its implicit vmcnt drain lands AFTER 16 MFMA + 8
// ds_read of latency cover). LDS = 2 x (16KB A + 8KB B) = 48KB.
// XOR-swizzled staging (linear LDS dest, swizzled global source + swizzled
// read -- both-sides rule) keeps ds_read_b128 conflicts low.
// Grid: 8 XCDs x 84 ctile-slots x 4 mtiles = 2688; the 4 mtiles of a ctile
// dispatch within 32 ids on one XCD -> 128KB B slab stays L2-hot across them.
__global__ __launch_bounds__(512, 4) void gemm_loss(const __hip_bfloat16* __restrict__ A,
                                                    const __hip_bfloat16* __restrict__ Wb,
                                                    float* __restrict__ wf,
                                                    float* __restrict__ rowsum) {
  const int id = blockIdx.x;
  const int xcd = id & 7;
  const int s = id >> 3;
  const int ctile = xcd * 84 + (s >> 2);
  if (ctile >= 670) return;  // 8 pad blocks
  const int mtile = s & 3;

  __shared__ __align__(16) char smem[2 * 24576];

  const int tid = threadIdx.x;
  const int lane = tid & 63;
  const int wav = tid >> 6;
  const int wm = wav >> 1, wn = wav & 1;  // 4 x 2 waves
  const int row0 = mtile * 256;
  const int col0 = ctile * 128;
  const int lr = lane & 15, lq = lane >> 4;
  const int waveBase = tid & ~63;

  f32x4 acc[4][4] = {};

  // ---- staging: A 256x32 bf16 (16KB, 1024 chunks of 16B, 2/thread),
  //               B 128x32 bf16 (8KB, 512 chunks, 1/thread)
  auto STAGE = [&](int b, int k0) {
    __hip_bfloat16* As = (__hip_bfloat16*)(smem + b * 24576);
    __hip_bfloat16* Bs = (__hip_bfloat16*)(smem + b * 24576 + 16384);
#pragma unroll
    for (int q = 0; q < 2; ++q) {
      const int chunk = q * 512 + tid;
      const int r = chunk >> 2, kc = chunk & 3;
      const int kcs = kc ^ (r & 3);  // slot kc holds global chunk kc^(r&3)
      async_ld16(A + ((size_t)(row0 + r) * DDIM + k0 + kcs * 8),
                 As + (q * 512 + waveBase) * 8);
    }
    {
      const int r = tid >> 2, kc = tid & 3;
      const int kcs = kc ^ (r & 3);
      int gr = col0 + r;
      gr = gr < CDIM ? gr : CDIM - 1;  // clamp address; masked in epilogue
      async_ld16(Wb + ((size_t)gr * DDIM + k0 + kcs * 8),
                 Bs + waveBase * 8);
    }
  };

  auto COMPUTE = [&](int b) {
    const __hip_bfloat16* As = (const __hip_bfloat16*)(smem + b * 24576);
    const __hip_bfloat16* Bs = (const __hip_bfloat16*)(smem + b * 24576 + 16384);
    bf16x8 af[4], bfr[4];
#pragma unroll
    for (int i = 0; i < 4; ++i) {
      const int ar = wm * 64 + i * 16 + lr;
      af[i] = *(const bf16x8*)(As + ar * 32 + (lq ^ (ar & 3)) * 8);
    }
#pragma unroll
    for (int j = 0; j < 4; ++j) {
      const int br = wn * 64 + j * 16 + lr;
      bfr[j] = *(const bf16x8*)(Bs + br * 32 + (lq ^ (br & 3)) * 8);
    }
#pragma unroll
    for (int i = 0; i < 4; ++i)
#pragma unroll
      for (int j = 0; j < 4; ++j)
        acc[i][j] = __builtin_amdgcn_mfma_f32_16x16x32_bf16(af[i], bfr[j], acc[i][j], 0, 0, 0);
  };

  STAGE(0, 0);
  __syncthreads();
#pragma unroll 1
  for (int k0 = 0; k0 < DDIM; k0 += 64) {
    STAGE(1, k0 + 32);  // k0+32 <= 480 < DDIM always
    COMPUTE(0);
    __syncthreads();
    if (k0 + 64 < DDIM) STAGE(0, k0 + 64);
    COMPUTE(1);
    __syncthreads();
  }

  // ---- epilogue: store wf (plain stores: L2 merges the misaligned-row
  // partial lines -- nt caused +155MB of RMW write traffic in round 1),
  // per-row exp-sum partials
#pragma unroll
  for (int i = 0; i < 4; ++i) {
    const int rb = row0 + wm * 64 + i * 16 + lq * 4;
#pragma unroll
    for (int r = 0; r < 4; ++r) {
      const int grow = rb + r;
      float esum = 0.f;
#pragma unroll
      for (int j = 0; j < 4; ++j) {
        const int gcol = col0 + wn * 64 + j * 16 + lr;
        const float v = acc[i][j][r];
        if (gcol < CDIM) {
          wf[(size_t)grow * CDIM + gcol] = v;
          esum += __expf(SSC * v);
        }
      }
      esum += __shfl_xor(esum, 1);
      esum += __shfl_xor(esum, 2);
      esum += __shfl_xor(esum, 4);
      esum += __shfl_xor(esum, 8);
      if (lr == 0) atomicAdd(rowsum + grow, esum);
    }
  }
}

// One block, 1024 threads: arcface loss from wf + rowsum.
__global__ void finalize(const float* __restrict__ wf, const float* __restrict__ rowsum,
                         const int* __restrict__ labels, float* __restrict__ out_loss) {
  const int i = threadIdx.x;
  const int lab = labels[i];
  const float tgt = wf[(size_t)i * CDIM + lab];
  const float tc = fminf(fmaxf(tgt, -1.0f + AEPS), 1.0f - AEPS);
  const float num = SSC * cosf(acosf(tc) + MARG);
  const float excl = rowsum[i] - __expf(SSC * tgt);
  float L = num - logf(__expf(num) + excl);
#pragma unroll
  for (int o = 32; o >= 1; o >>= 1) L += __shfl_xor(L, o);
  __shared__ float red[16];
  if ((i & 63) == 0) red[i >> 6] = L;
  __syncthreads();
  if (i < 64) {
    float v = (i < 16) ? red[i] : 0.f;
#pragma unroll
    for (int o = 8; o >= 1; o >>= 1) v += __shfl_xor(v, o);
    if (i == 0) out_loss[0] = -v * (1.0f / NROW);
  }
}

extern "C" void kernel_launch(void* const* d_in, const int* in_sizes, int n_in,
                              void* d_out, int out_size, void* d_ws, size_t ws_size,
                              hipStream_t stream) {
  const float* x = (const float*)d_in[0];
  const float* W = (const float*)d_in[1];
  const int* labels = (const int*)d_in[2];
  float* out = (float*)d_out;

  // workspace layout (round-1 verified: ws_size >= 89MB, bf16 path taken):
  //   [0,4K)            rowsum fp32[1024]
  //   [4K, 4K+1M)       xn bf16[1024*512]
  //   [4K+1M, +87.8M)   Wb bf16[85742*512]
  float* rowsum = (float*)d_ws;
  __hip_bfloat16* xn = (__hip_bfloat16*)((char*)d_ws + 4096);
  const size_t wb_off = 4096 + (size_t)NROW * DDIM * 2;
  __hip_bfloat16* Wb = (__hip_bfloat16*)((char*)d_ws + wb_off);

  prep<<<2304, 256, 0, stream>>>(x, W, xn, Wb, rowsum);
  gemm_loss<<<2688, 512, 0, stream>>>(xn, Wb, out, rowsum);
  finalize<<<1, 1024, 0, stream>>>(out, rowsum, labels, out + (size_t)NROW * CDIM);
}